// Round 18
// baseline (181.553 us; speedup 1.0000x reference)
//
#include <hip/hip_runtime.h>
#include <hip/hip_bf16.h>

// Problem constants
#define D    1024
#define LD   64
#define NTR  8192
#define NT   8192
#define DY   128

#define SHIFT 40.0f
#define NCHUNK 16
#define CHUNK (NTR / NCHUNK)   // 512 train rows per chunk = 16 tiles of 32

typedef __attribute__((ext_vector_type(8))) short bf16x8;      // generic 8x16-bit
typedef __attribute__((ext_vector_type(8))) _Float16 half8;    // fp16 MFMA operand
typedef __attribute__((ext_vector_type(4))) short short4_;
typedef __attribute__((ext_vector_type(4))) float f4;

static __device__ __forceinline__ short f2bf(float f) {
    __hip_bfloat16 h = __float2bfloat16(f);
    short s; __builtin_memcpy(&s, &h, 2); return s;
}
static __device__ __forceinline__ float bf2f(short s) {
    __hip_bfloat16 h; __builtin_memcpy(&h, &s, 2); return __bfloat162float(h);
}
static __device__ __forceinline__ short f2h(float f) {
    _Float16 h = (_Float16)f;
    short s; __builtin_memcpy(&s, &h, 2); return s;
}
static __device__ __forceinline__ float h2f(short s) {
    _Float16 h; __builtin_memcpy(&h, &s, 2); return (float)h;
}

// async global->LDS DMA, 16 B per lane: LDS dest = wave-uniform base + lane*16
static __device__ __forceinline__ void gload_lds16(const void* g, void* l) {
    __builtin_amdgcn_global_load_lds(
        (const __attribute__((address_space(1))) unsigned int*)g,
        (__attribute__((address_space(3))) unsigned int*)l,
        16, 0, 0);
}

// s_waitcnt vmcnt(8), lgkmcnt/expcnt masked
#define WAIT_VM8() __builtin_amdgcn_s_waitcnt(0x3F78)

// ---------------------------------------------------------------------------
// K0: A[D][LD] f32 -> col-major bf16 hi/lo split AT[LD][D].  64 blocks.
// ---------------------------------------------------------------------------
__global__ __launch_bounds__(256) void prep_A(const float* __restrict__ A,
                                              short* __restrict__ AThi,
                                              short* __restrict__ ATlo) {
    int k = blockIdx.x * 16 + (threadIdx.x >> 4);
    int c0 = (threadIdx.x & 15) * 4;
    f4 a = *(const f4*)&A[(long)k * LD + c0];
    #pragma unroll
    for (int j = 0; j < 4; ++j) {
        int c = c0 + j;
        short hi = f2bf(a[j]);
        AThi[(long)c * D + k] = hi;
        ATlo[(long)c * D + k] = f2bf(a[j] - bf2f(hi));
    }
}

// ---------------------------------------------------------------------------
// K1 (fused proj + V-prep, 512 blocks):
//   blocks   0..255 : projection — each WAVE owns 16 rows x 64 cols;
//                     x staged into PRIVATE LDS via global_load_lds
//                     (triple-buffered 2-ahead, vmcnt-synced, no barriers);
//                     A-fragments = 4 b128 loads from precomputed AT (L2-hot).
//                     Outputs: qt fp16 hi/lo (UNCENTERED), ktr fp16 swizzled,
//                     muAp partial slots (no atomics, no zero-init).
//   blocks 256..511 : ytr -> swizzled V tiles (bf16); tile aliased into smem.
// ---------------------------------------------------------------------------
__global__ __launch_bounds__(256) void proj_prep(const float* __restrict__ xt,
                                                 const float* __restrict__ xtr,
                                                 const short* __restrict__ AThi,
                                                 const short* __restrict__ ATlo,
                                                 const float* __restrict__ ytr,
                                                 short* __restrict__ qt_hi,
                                                 short* __restrict__ qt_lo,
                                                 short* __restrict__ ktr,
                                                 float* __restrict__ muAp,
                                                 short* __restrict__ vtile) {
    __shared__ __align__(16) float smem[12288];   // 48 KB, aliased per role

    int tid = threadIdx.x;
    int b = blockIdx.x;

    if (b >= 256) {
        // ---- ytr transpose -> swizzled V tiles (bf16) ----
        float (*tile)[66] = (float (*)[66])smem;   // 64x66 = 16.9 KB < 48 KB
        int bz = b - 256;
        int t0 = (bz & 127) * 64;
        int d0 = (bz >> 7) * 64;
        int c = tid & 63;
        int r4 = tid >> 6;
        #pragma unroll
        for (int i = 0; i < 16; ++i) {
            int r = i * 4 + r4;
            tile[r][c] = ytr[(long)(t0 + r) * DY + d0 + c];
        }
        __syncthreads();
        #pragma unroll
        for (int i = 0; i < 16; ++i) {
            int r = i * 4 + r4;       // dy local
            int t = t0 + c;
            int dy = d0 + r;
            long idx = (long)(t >> 5) * 4096 + (long)dy * 32
                     + ((((t >> 3) & 3) ^ (dy & 3)) << 3) + (t & 7);
            vtile[idx] = f2bf(tile[c][r]);
        }
        return;
    }

    // ---- projection (wave-private, barrier-free) ----
    float (*xbuf)[3][1024] = (float (*)[3][1024])smem;   // [wave][buf][16x64]

    int wave = tid >> 6;
    int lane = tid & 63;
    int quad = lane >> 4;
    int l16 = lane & 15;

    int g = b * 4 + wave;                 // 0..1023 row-groups of 16
    bool is_test = g < (NT / 16);
    int row0 = (is_test ? g : g - NT / 16) * 16;
    const float* x = is_test ? xt : xtr;

    int sr = lane >> 4;                   // 0..3
    int cg0 = (lane & 15);                // stored pos

    f4 acc[4];
    #pragma unroll
    for (int ct = 0; ct < 4; ++ct) acc[ct] = (f4){0.f, 0.f, 0.f, 0.f};

    int pr0 = ((quad * 2) ^ (l16 & 7)) * 4;
    int pr1 = (((quad * 2) | 1) ^ (l16 & 7)) * 4;

#define PROJ_DMA(S, BUF)                                                        \
    {                                                                           \
        int kk0 = ((S) & 15) * 64;                                              \
        _Pragma("unroll")                                                       \
        for (int j = 0; j < 4; ++j) {                                           \
            int r = j * 4 + sr;                                                 \
            int cgl = cg0 ^ (r & 7);                                            \
            gload_lds16(x + (long)(row0 + r) * D + kk0 + cgl * 4,               \
                        &xbuf[wave][BUF][j * 256]);                             \
        }                                                                       \
    }

    PROJ_DMA(0, 0)
    PROJ_DMA(1, 1)

    #pragma unroll 1
    for (int s = 0; s < 16; ++s) {
        int cur = s % 3;
        PROJ_DMA(s + 2, (s + 2) % 3)      // wraps past 15 (harmless re-read)
        WAIT_VM8();                        // step s's 4 gloads complete

        const float* xrow = &xbuf[wave][cur][l16 * 64];
        bf16x8 ah[2], al[2];
        #pragma unroll
        for (int h = 0; h < 2; ++h) {
            f4 v0 = *(const f4*)(xrow + h * 32 + pr0);
            f4 v1 = *(const f4*)(xrow + h * 32 + pr1);
            #pragma unroll
            for (int e = 0; e < 4; ++e) {
                short hi0 = f2bf(v0[e]);
                short hi1 = f2bf(v1[e]);
                ah[h][e]     = hi0;
                ah[h][e + 4] = hi1;
                al[h][e]     = f2bf(v0[e] - bf2f(hi0));
                al[h][e + 4] = f2bf(v1[e] - bf2f(hi1));
            }
        }

        int k0 = s * 64;
        #pragma unroll
        for (int ct = 0; ct < 4; ++ct) {
            const short* bh = AThi + (long)(ct * 16 + l16) * D + k0 + quad * 8;
            const short* bl = ATlo + (long)(ct * 16 + l16) * D + k0 + quad * 8;
            bf16x8 bh0 = *(const bf16x8*)bh;
            bf16x8 bh1 = *(const bf16x8*)(bh + 32);
            bf16x8 bl0 = *(const bf16x8*)bl;
            bf16x8 bl1 = *(const bf16x8*)(bl + 32);
            f4 a = acc[ct];
            a = __builtin_amdgcn_mfma_f32_16x16x32_bf16(ah[0], bh0, a, 0, 0, 0);
            a = __builtin_amdgcn_mfma_f32_16x16x32_bf16(al[0], bh0, a, 0, 0, 0);
            a = __builtin_amdgcn_mfma_f32_16x16x32_bf16(ah[0], bl0, a, 0, 0, 0);
            a = __builtin_amdgcn_mfma_f32_16x16x32_bf16(ah[1], bh1, a, 0, 0, 0);
            a = __builtin_amdgcn_mfma_f32_16x16x32_bf16(al[1], bh1, a, 0, 0, 0);
            a = __builtin_amdgcn_mfma_f32_16x16x32_bf16(ah[1], bl1, a, 0, 0, 0);
            acc[ct] = a;
        }
    }
#undef PROJ_DMA

    #pragma unroll
    for (int ct = 0; ct < 4; ++ct) {
        int col = ct * 16 + l16;
        #pragma unroll
        for (int r = 0; r < 4; ++r) {
            int grow = row0 + quad * 4 + r;
            float qv = acc[ct][r];
            if (is_test) {
                short hi = f2h(qv);
                qt_hi[(long)grow * LD + col] = hi;
                qt_lo[(long)grow * LD + col] = f2h(qv - h2f(hi));
            } else {
                int tl = grow & 31;
                long idx = (long)(grow >> 5) * 2048 + tl * 64
                         + ((((col >> 3) ^ (tl & 7))) << 3) + (col & 7);
                ktr[idx] = f2h(qv);
            }
        }
        if (!is_test) {
            float s = acc[ct][0] + acc[ct][1] + acc[ct][2] + acc[ct][3];
            s += __shfl_xor(s, 16);
            s += __shfl_xor(s, 32);
            if (quad == 0) muAp[(long)(g - NT / 16) * 64 + col] = s;
        }
    }
}

// ---------------------------------------------------------------------------
// K2: flash attention, q=64/wave (rt=4).  Q centering FUSED into prologue:
// each block reduces muAp (L2-hot, ~128 KB) -> muA, then centers its Q
// fragments in-register (k-side centering cancels; constant SHIFT).
// Grid 512 = 32 Q-slabs(256 rows) x 16 K-chunks(512); 2 blocks/CU.
// K fp16 + V bf16 staged via global_load_lds (double-buffered, 1 barrier/iter).
// ---------------------------------------------------------------------------
__global__ __launch_bounds__(256, 2) void flash_kernel(const short* __restrict__ qt_hi,
                                                       const short* __restrict__ qt_lo,
                                                       const short* __restrict__ ksw,
                                                       const short* __restrict__ vtile,
                                                       const float* __restrict__ muAp,
                                                       short* __restrict__ Opart,
                                                       float* __restrict__ Lpart) {
    __shared__ __align__(16) short kbh[2][2048];    //  8 KB  K fp16 tiles
    __shared__ __align__(16) short vbuf[2][4096];   // 16 KB  V bf16 tiles
    __shared__ __align__(16) short ptile[4][2560];  // 20 KB  per-wave P[64][32] pitch 40
    __shared__ float redm[4][64];
    __shared__ float muAs[64];

    int tid = threadIdx.x;
    int wave = tid >> 6;
    int lane = tid & 63;
    int quad = lane >> 4;
    int l16 = lane & 15;

    int kc = blockIdx.x & 15;             // K-chunk; %8 residue -> XCD-affine
    int qi = blockIdx.x >> 4;             // 0..31
    int q0w = qi * 256 + wave * 64;
    int tile0 = kc * 16;                  // 16 tiles of 32 per chunk

    int soff = wave * 512 + lane * 8;     // staging src offset (shorts)
    int ldso = wave * 512;                // staging LDS base (wave-uniform)

    // ---- muA reduction (all threads) ----
    {
        int l = tid & 63;
        int gg = tid >> 6;
        float ms = 0.f;
        #pragma unroll 8
        for (int p = gg; p < 512; p += 4) ms += muAp[(long)p * 64 + l];
        redm[gg][l] = ms;
    }
    // also kick off tile-0 staging before the barrier
    gload_lds16(ksw + (long)tile0 * 2048 + soff, &kbh[0][ldso]);
    gload_lds16(vtile + (long)tile0 * 4096 + soff, &vbuf[0][ldso]);
    gload_lds16(vtile + (long)tile0 * 4096 + 2048 + soff, &vbuf[0][2048 + ldso]);
    __syncthreads();
    if (tid < 64)
        muAs[tid] = (redm[0][tid] + redm[1][tid] + redm[2][tid] + redm[3][tid]) *
                    (1.0f / (float)NTR);
    __syncthreads();

    // ---- Q fragments, fp16 hi/lo, centered in-register ----
    half8 qh[4][2], ql[4][2];
    #pragma unroll
    for (int rt = 0; rt < 4; ++rt) {
        const short* qrh = qt_hi + (long)(q0w + rt * 16 + l16) * LD + quad * 8;
        const short* qrl = qt_lo + (long)(q0w + rt * 16 + l16) * LD + quad * 8;
        #pragma unroll
        for (int h = 0; h < 2; ++h) {
            bf16x8 hbits = *(const bf16x8*)(qrh + h * 32);
            bf16x8 lbits = *(const bf16x8*)(qrl + h * 32);
            half8 nh, nl;
            #pragma unroll
            for (int e = 0; e < 8; ++e) {
                float qc = h2f(hbits[e]) + h2f(lbits[e]) - muAs[h * 32 + quad * 8 + e];
                _Float16 hh = (_Float16)qc;
                nh[e] = hh;
                nl[e] = (_Float16)(qc - (float)hh);
            }
            qh[rt][h] = nh;
            ql[rt][h] = nl;
        }
    }

    bf16x8 onef;
    #pragma unroll
    for (int i = 0; i < 8; ++i) onef[i] = (short)0x3F80;   // bf16(1.0)

    f4 Ov[4][8];
    f4 Lv[4];
    #pragma unroll
    for (int rt = 0; rt < 4; ++rt) {
        Lv[rt] = (f4){0.f, 0.f, 0.f, 0.f};
        #pragma unroll
        for (int jt = 0; jt < 8; ++jt) Ov[rt][jt] = (f4){0.f, 0.f, 0.f, 0.f};
    }

    short* myp = &ptile[wave][0];
    const int p0 = ((quad ^ (l16 & 7)) << 3);          // K chunk pos; h2=1 -> ^32
    const int pv = ((quad ^ (l16 & 3)) << 3);          // V chunk pos

    #pragma unroll 1
    for (int it = 0; it < 16; ++it) {
        int cur = it & 1;

        if (it < 15) {
            int nb = cur ^ 1;
            long tb = (long)(tile0 + it + 1);
            gload_lds16(ksw + tb * 2048 + soff, &kbh[nb][ldso]);
            gload_lds16(vtile + tb * 4096 + soff, &vbuf[nb][ldso]);
            gload_lds16(vtile + tb * 4096 + 2048 + soff, &vbuf[nb][2048 + ldso]);
        }

        half8 kh[2][2];                    // [tt][h2], fp16 — read ONCE, used 4x
        #pragma unroll
        for (int tt = 0; tt < 2; ++tt) {
            int rb = (tt * 16 + l16) * 64;
            kh[tt][0] = *(const half8*)&kbh[cur][rb + p0];
            kh[tt][1] = *(const half8*)&kbh[cur][rb + (p0 ^ 32)];
        }

        // S^T per row-tile; exp; P -> LDS (b64 packed)
        #pragma unroll
        for (int rt = 0; rt < 4; ++rt) {
            #pragma unroll
            for (int tt = 0; tt < 2; ++tt) {
                f4 a = (f4){0.f, 0.f, 0.f, 0.f};
                a = __builtin_amdgcn_mfma_f32_16x16x32_f16(kh[tt][0], qh[rt][0], a, 0, 0, 0);
                a = __builtin_amdgcn_mfma_f32_16x16x32_f16(kh[tt][0], ql[rt][0], a, 0, 0, 0);
                a = __builtin_amdgcn_mfma_f32_16x16x32_f16(kh[tt][1], qh[rt][1], a, 0, 0, 0);
                a = __builtin_amdgcn_mfma_f32_16x16x32_f16(kh[tt][1], ql[rt][1], a, 0, 0, 0);
                short4_ p4;
                p4[0] = f2bf(__expf(a[0] - SHIFT));
                p4[1] = f2bf(__expf(a[1] - SHIFT));
                p4[2] = f2bf(__expf(a[2] - SHIFT));
                p4[3] = f2bf(__expf(a[3] - SHIFT));
                *(short4_*)&myp[(rt * 16 + l16) * 40 + tt * 16 + quad * 4] = p4;
            }
        }

        // P fragments (one b128 per rt), V amortized across all 4 rt
        bf16x8 pf[4];
        #pragma unroll
        for (int rt = 0; rt < 4; ++rt)
            pf[rt] = *(const bf16x8*)&myp[(rt * 16 + l16) * 40 + quad * 8];
        #pragma unroll
        for (int jt = 0; jt < 8; ++jt) {
            bf16x8 vf = *(const bf16x8*)&vbuf[cur][(jt * 16 + l16) * 32 + pv];
            #pragma unroll
            for (int rt = 0; rt < 4; ++rt)
                Ov[rt][jt] = __builtin_amdgcn_mfma_f32_16x16x32_bf16(pf[rt], vf, Ov[rt][jt], 0, 0, 0);
        }
        #pragma unroll
        for (int rt = 0; rt < 4; ++rt)
            Lv[rt] = __builtin_amdgcn_mfma_f32_16x16x32_bf16(pf[rt], onef, Lv[rt], 0, 0, 0);

        __syncthreads();
    }

    long ob = (long)kc * NT;
    #pragma unroll
    for (int rt = 0; rt < 4; ++rt) {
        #pragma unroll
        for (int jt = 0; jt < 8; ++jt) {
            #pragma unroll
            for (int r = 0; r < 4; ++r)
                Opart[(ob + q0w + rt * 16 + quad * 4 + r) * DY + jt * 16 + l16] =
                    f2bf(Ov[rt][jt][r]);
        }
        if (l16 == 0) {
            #pragma unroll
            for (int r = 0; r < 4; ++r)
                Lpart[ob + q0w + rt * 16 + quad * 4 + r] = Lv[rt][r];
        }
    }
}

// ---------------------------------------------------------------------------
// K3: out[q][dy] = sum_kc Opart[kc][q][dy] / sum_kc Lpart[kc][q]  (bf16 parts)
// ---------------------------------------------------------------------------
__global__ __launch_bounds__(256) void finalize_kernel(const short* __restrict__ Opart,
                                                       const float* __restrict__ Lpart,
                                                       float* __restrict__ out) {
    long i = ((long)blockIdx.x * 256 + threadIdx.x) * 8;
    long row = i >> 7;          // DY = 128
    float L = 0.f;
    f4 a = (f4){0.f, 0.f, 0.f, 0.f};
    f4 b = (f4){0.f, 0.f, 0.f, 0.f};
    #pragma unroll
    for (int kc = 0; kc < NCHUNK; ++kc) {
        L += Lpart[(long)kc * NT + row];
        bf16x8 o = *(const bf16x8*)&Opart[(long)kc * NT * DY + i];
        #pragma unroll
        for (int j = 0; j < 4; ++j) {
            a[j] += bf2f(o[j]);
            b[j] += bf2f(o[j + 4]);
        }
    }
    float linv = 1.0f / L;
    a *= linv; b *= linv;
    *(f4*)&out[i] = a;
    *(f4*)&out[i + 4] = b;
}

// ---------------------------------------------------------------------------
extern "C" void kernel_launch(void* const* d_in, const int* in_sizes, int n_in,
                              void* d_out, int out_size, void* d_ws, size_t ws_size,
                              hipStream_t stream) {
    const float* xtr = (const float*)d_in[0];   // [NTR, D]
    const float* ytr = (const float*)d_in[1];   // [NTR, DY]
    const float* xt  = (const float*)d_in[2];   // [NT, D]
    const float* A   = (const float*)d_in[3];   // [D, LD]
    float* out = (float*)d_out;                 // [NT, DY]

    // workspace carving (no memset needed: muAp slots are fully written)
    char* w = (char*)d_ws;
    float* muAp  = (float*)w; w += (size_t)512 * 64 * 4;          // 128 KB
    float* Lpart = (float*)w; w += (size_t)NCHUNK * NT * 4;       // 512 KB
    short* Opart = (short*)w; w += (size_t)NCHUNK * NT * DY * 2;  // 32 MB (bf16)
    short* AThi  = (short*)w; w += (size_t)LD * D * 2;            // 128 KB
    short* ATlo  = (short*)w; w += (size_t)LD * D * 2;
    short* qt_hi  = (short*)w; w += (size_t)NT * LD * 2;          // 1 MB each (fp16)
    short* qt_lo  = (short*)w; w += (size_t)NT * LD * 2;
    short* ksw    = (short*)w; w += (size_t)NTR * LD * 2;         // fp16 swizzled tiles
    short* vtile  = (short*)w; w += (size_t)DY * NTR * 2;         // 2 MB bf16 swizzled
    (void)ws_size; (void)in_sizes; (void)n_in; (void)out_size;

    prep_A<<<64, 256, 0, stream>>>(A, AThi, ATlo);
    proj_prep<<<512, 256, 0, stream>>>(xt, xtr, AThi, ATlo, ytr,
                                       qt_hi, qt_lo, ksw, muAp, vtile);
    flash_kernel<<<512, 256, 0, stream>>>(qt_hi, qt_lo, ksw, vtile, muAp,
                                          Opart, Lpart);
    finalize_kernel<<<(NT * DY) / (256 * 8), 256, 0, stream>>>(Opart, Lpart, out);
}